// Round 2
// baseline (19276.111 us; speedup 1.0000x reference)
//
#include <hip/hip_runtime.h>
#include <math.h>

// T=2048, B=16, D=1024
//   Wx_all[t,b,e] = sum_d x[t,b,d] * W_x[e,d] + b[e]
//   scan: pre = h @ W_h^T + wx_t ; h += alpha*tanh(pre) ; out = h^2 * sigmoid(h)
// d_out layout: outs [T,B,D] floats, then h [T+1,B,D] floats.
// outs region doubles as the Wx_all buffer (read wx[t], overwrite with out[t]).
//
// Round 4: batch-split domains + data-flag sync (no barrier, no syncthreads in
// the scan loop).
//   - 8 independent domains (2 batch elements each): the 16 batch recurrences
//     are independent; sync domain shrinks from 128 WGs to 32 WGs (128 waves).
//   - per-WAVE monotone flags: producer wave stores its 64 h-values (sc1,
//     agent-relaxed), s_waitcnt vmcnt(0), then stores flag=t+1. Consumers poll
//     all 128 domain flags with ONE wave-wide atomic load + ballot. No atomic
//     RMW tree, no root counter, no convoy.
//   - flag prefetch issued BEFORE the store-drain waitcnt: in steady state the
//     poll RTT hides under the drain.
//   - h[t] read directly from L2/IC (8 KB/domain, broadcast-coalesced); W_h
//     slice (32 rows, 131.6 KB, stride-257 padded -> conflict-free b128 reads)
//     LDS-resident. Reduction via shfl_xor butterfly (no red[] LDS traffic).
// Safety invariant (same as round 3): every h address is written exactly once
// and read only after its producer's flag -> plain cached reads can never be
// stale; relaxed agent atomics suffice (no buffer_wbl2/buffer_inv anywhere).

#define T_STEPS 2048
#define BATCH 16
#define DIM 1024
#define NDOM 8              // batch-pair domains
#define WPD 32              // WGs per domain
#define NWG (NDOM * WPD)    // 256 = one per CU
#define COLS 32             // output columns per WG
#define WSTRIDE 257         // float4 stride per W_h row (+16B pad: bank shift)

__device__ __forceinline__ float dot4(float4 a, float4 b) {
    return a.x * b.x + a.y * b.y + a.z * b.z + a.w * b.w;
}

// ---------------- GEMM: C[m,n] = sum_k X[m,k]*W[n,k] + bias[n] ----------------
__global__ __launch_bounds__(256) void gemm_wx_kernel(
    const float* __restrict__ X,     // [M, K]
    const float* __restrict__ W,     // [N, K]
    const float* __restrict__ bias,  // [N]
    float* __restrict__ C)           // [M, N]
{
    const int K = DIM, N = DIM;
    __shared__ float Xs[64][17];
    __shared__ float Ws[64][17];
    const int tid = threadIdx.x;
    const int m0 = blockIdx.x * 64;
    const int n0 = blockIdx.y * 64;
    const int ty = tid >> 4;
    const int tx = tid & 15;
    float acc[4][4] = {};

    for (int k0 = 0; k0 < K; k0 += 16) {
#pragma unroll
        for (int i = 0; i < 4; i++) {
            int idx = tid + i * 256;
            int r = idx >> 4;
            int c = idx & 15;
            Xs[r][c] = X[(size_t)(m0 + r) * K + (k0 + c)];
            Ws[r][c] = W[(size_t)(n0 + r) * K + (k0 + c)];
        }
        __syncthreads();
#pragma unroll
        for (int kk = 0; kk < 16; kk++) {
            float a[4], w[4];
#pragma unroll
            for (int i = 0; i < 4; i++) a[i] = Xs[ty * 4 + i][kk];
#pragma unroll
            for (int j = 0; j < 4; j++) w[j] = Ws[tx * 4 + j][kk];
#pragma unroll
            for (int i = 0; i < 4; i++)
#pragma unroll
                for (int j = 0; j < 4; j++)
                    acc[i][j] += a[i] * w[j];
        }
        __syncthreads();
    }
#pragma unroll
    for (int i = 0; i < 4; i++) {
        int m = m0 + ty * 4 + i;
#pragma unroll
        for (int j = 0; j < 4; j++) {
            int n = n0 + tx * 4 + j;
            C[(size_t)m * N + n] = acc[i][j] + bias[n];
        }
    }
}

// ---------------- h[0] = h0 ----------------
__global__ __launch_bounds__(256) void copy_h0_kernel(
    const float* __restrict__ h0, float* __restrict__ h)
{
    int i = blockIdx.x * 256 + threadIdx.x;
    if (i < BATCH * DIM) h[i] = h0[i];
}

// ---------------- flag init (d_ws is poisoned each launch) ----------------
__global__ void flag_init_kernel(unsigned int* flags)
{
    flags[threadIdx.x] = 0u;   // 1024 flags = NDOM*WPD*4 waves
}

// ---------------- persistent scan ----------------
// WG (dom = bid&7, wgl = bid>>3): columns [wgl*32, wgl*32+32), batches
// {dom*2, dom*2+1}. Wave w owns cols [wgl*32 + w*8, +8).
// Thread map: lane = kg*4 + pg (kg in [0,16) k-groups, pg in [0,4) col-pairs).
// Per thread: 4 accumulators = pairs (c = pg*2 + i>>1, b = i&1), i=0..3.
// k-slices: per sc (0..3), per m (0..3): k4 = sc*64 + kg + 16*m.
// Reduce over kg via shfl_xor masks 4..32; finisher lanes 0..15 per wave.
__global__ __launch_bounds__(256, 1) void rnn_scan_kernel(
    const float* __restrict__ Wh,         // [D, D]
    const float* __restrict__ log_alpha,  // [1]
    float* __restrict__ outs,             // [T,B,D] (wx in, out overwritten)
    float* __restrict__ h,                // [T+1,B,D]
    unsigned int* __restrict__ flags)     // [NDOM*128] wave flags (zeroed)
{
    __shared__ float4 whs4[COLS * WSTRIDE];   // 131.6 KB -> 1 WG/CU

    const int tid = threadIdx.x;
    const int bid = blockIdx.x;
    const int dom = bid & 7;
    const int wgl = bid >> 3;            // 0..31
    const int e0  = wgl * COLS;
    const int b0  = dom * 2;             // global batch base

    // ---- preload W_h rows for this WG (once) ----
    const float4* wh4 = (const float4*)Wh;
#pragma unroll
    for (int i = 0; i < 32; i++) {
        int idx = tid + i * 256;
        int r = idx >> 8, f = idx & 255;
        whs4[r * WSTRIDE + f] = wh4[(size_t)(e0 + r) * 256 + f];
    }
    const float alpha = expf(log_alpha[0]);
    __syncthreads();   // whs ready -- the ONLY workgroup barrier

    const int w    = tid >> 6;           // wave 0..3
    const int lane = tid & 63;
    const int kg   = lane >> 2;          // 0..15
    const int pg   = lane & 3;           // 0..3

    // finisher mapping (valid for lane < 16): lane = f_i*4 + f_pg
    const int f_i  = lane >> 2;          // selects acc / (col,b) pair
    const int f_pg = lane & 3;
    const int f_b  = b0 + (f_i & 1);
    const int f_e  = e0 + w * 8 + f_pg * 2 + (f_i >> 1);

    // W_h LDS row bases for this thread's two columns
    const int wbase0 = (w * 8 + pg * 2 + 0) * WSTRIDE;
    const int wbase1 = (w * 8 + pg * 2 + 1) * WSTRIDE;

    // flags: domain-local block of 128 (32 WGs x 4 waves)
    unsigned int* const fl = flags + dom * 128;
    const int own = wgl * 4 + w;
    const bool skip0 = (lane == own);
    const bool skip1 = (lane + 64 == own);
    unsigned int* const ownp = fl + own;

    unsigned int fv0 = __hip_atomic_load(&fl[lane],      __ATOMIC_RELAXED, __HIP_MEMORY_SCOPE_AGENT);
    unsigned int fv1 = __hip_atomic_load(&fl[lane + 64], __ATOMIC_RELAXED, __HIP_MEMORY_SCOPE_AGENT);

    for (int t = 0; t < T_STEPS; t++) {
        // ---- wait: all producer waves of this domain have published h[t] ----
        for (;;) {
            bool ok = (skip0 || fv0 >= (unsigned)t) && (skip1 || fv1 >= (unsigned)t);
            if (__ballot(ok) == ~0ull) break;
            __builtin_amdgcn_s_sleep(1);
            fv0 = __hip_atomic_load(&fl[lane],      __ATOMIC_RELAXED, __HIP_MEMORY_SCOPE_AGENT);
            fv1 = __hip_atomic_load(&fl[lane + 64], __ATOMIC_RELAXED, __HIP_MEMORY_SCOPE_AGENT);
        }
        __builtin_amdgcn_sched_barrier(0);  // keep h loads below the spin exit

        const float*  hp  = h + (size_t)t * (BATCH * DIM);
        const float4* hp4 = (const float4*)hp;    // index: b*256 + k4

        // ---- finisher prefetch (wx from GEMM output, hprev) ----
        float wx = 0.f, hprev = 0.f;
        size_t oidx = 0;
        if (lane < 16) {
            oidx  = (size_t)t * (BATCH * DIM) + (size_t)f_b * DIM + f_e;
            wx    = outs[oidx];
            hprev = hp[(size_t)f_b * DIM + f_e];
        }

        // ---- partial dot products: 2 cols x 2 batches per thread ----
        float acc0 = 0.f, acc1 = 0.f, acc2 = 0.f, acc3 = 0.f;
#pragma unroll
        for (int sc = 0; sc < 4; sc++) {
            const int k4b = sc * 64 + kg;
#pragma unroll
            for (int m = 0; m < 4; m++) {
                const int k4 = k4b + 16 * m;
                float4 hv0 = hp4[(b0 + 0) * 256 + k4];   // L2/IC broadcast
                float4 hv1 = hp4[(b0 + 1) * 256 + k4];
                float4 w0  = whs4[wbase0 + k4];
                float4 w1  = whs4[wbase1 + k4];
                acc0 += dot4(w0, hv0);
                acc1 += dot4(w0, hv1);
                acc2 += dot4(w1, hv0);
                acc3 += dot4(w1, hv1);
            }
        }

        // ---- butterfly reduce over kg (lane bits 2..5) ----
#pragma unroll
        for (int mask = 4; mask <= 32; mask <<= 1) {
            acc0 += __shfl_xor(acc0, mask);
            acc1 += __shfl_xor(acc1, mask);
            acc2 += __shfl_xor(acc2, mask);
            acc3 += __shfl_xor(acc3, mask);
        }

        // ---- finish: nonlinearity, publish h[t+1], write out[t] ----
        if (lane < 16) {
            float s = (f_i == 0) ? acc0 : (f_i == 1) ? acc1
                    : (f_i == 2) ? acc2 : acc3;
            const float pre  = s + wx;
            const float hnew = hprev + alpha * tanhf(pre);
            // agent-relaxed sc1 store -> Infinity Cache (agent coherence point)
            __hip_atomic_store(
                &h[(size_t)(t + 1) * (BATCH * DIM) + (size_t)f_b * DIM + f_e],
                hnew, __ATOMIC_RELAXED, __HIP_MEMORY_SCOPE_AGENT);
            const float sig = 1.f / (1.f + expf(-hnew));
            outs[oidx] = hnew * hnew * sig;   // plain store, flushed at kernel end
        }

        // ---- prefetch next poll (hides poll RTT under the store drain) ----
        fv0 = __hip_atomic_load(&fl[lane],      __ATOMIC_RELAXED, __HIP_MEMORY_SCOPE_AGENT);
        fv1 = __hip_atomic_load(&fl[lane + 64], __ATOMIC_RELAXED, __HIP_MEMORY_SCOPE_AGENT);

        // ---- drain our stores to the coherence point, then publish flag ----
        asm volatile("s_waitcnt vmcnt(0)" ::: "memory");
        __hip_atomic_store(ownp, (unsigned)(t + 1),
                           __ATOMIC_RELAXED, __HIP_MEMORY_SCOPE_AGENT);
    }
}

extern "C" void kernel_launch(void* const* d_in, const int* in_sizes, int n_in,
                              void* d_out, int out_size, void* d_ws, size_t ws_size,
                              hipStream_t stream) {
    const float* x         = (const float*)d_in[0];  // [T,B,D]
    const float* h0        = (const float*)d_in[1];  // [B,D]
    const float* W_x       = (const float*)d_in[2];  // [D,D]
    const float* W_h       = (const float*)d_in[3];  // [D,D]
    const float* bias      = (const float*)d_in[4];  // [D]
    const float* log_alpha = (const float*)d_in[5];  // [1]

    float* outs = (float*)d_out;                                  // [T,B,D]
    float* h    = (float*)d_out + (size_t)T_STEPS * BATCH * DIM;  // [T+1,B,D]
    unsigned int* flags = (unsigned int*)d_ws;

    // 1) Wx_all (+bias) -> outs region. M = T*B = 32768 rows.
    dim3 ggrid(32768 / 64, DIM / 64);
    gemm_wx_kernel<<<ggrid, 256, 0, stream>>>(x, W_x, bias, outs);

    // 2) h[0] = h0 ; wave flags = 0
    copy_h0_kernel<<<(BATCH * DIM + 255) / 256, 256, 0, stream>>>(h0, h);
    flag_init_kernel<<<1, 1024, 0, stream>>>(flags);

    // 3) persistent scan: 256 WGs = 1 per CU (131.6 KB LDS each)
    rnn_scan_kernel<<<NWG, 256, 0, stream>>>(W_h, log_alpha, outs, h, flags);
}

// Round 3
// 13512.991 us; speedup vs baseline: 1.4265x; 1.4265x over previous
//
#include <hip/hip_runtime.h>
#include <math.h>

// T=2048, B=16, D=1024
//   Wx_all[t,b,e] = sum_d x[t,b,d] * W_x[e,d] + b[e]
//   scan: pre = h @ W_h^T + wx_t ; h += alpha*tanh(pre) ; out = h^2 * sigmoid(h)
// d_out layout: outs [T,B,D] floats, then h [T+1,B,D] floats.
// outs region doubles as the Wx_all buffer (read wx[t], overwrite with out[t]).
//
// Round 5: round-3 dataflow (LDS-staged h, LDS-resident W slice, coalesced
// staging) + round-4 cheap sync (monotone data flags, no ACQ_REL/fence), with
// every serial-chain term shrunk:
//   - 4 domains x 64 WGs x 4 batches (batch recurrences independent). WG =
//     16 cols x 4 batches: W slice 65.8KB + h stage 16.4KB + red 1KB = 83KB.
//   - ONE flag per WG (64/domain): single wave-wide sc1 load polls the whole
//     domain; prefetched at loop bottom so the RTT hides in steady state.
//   - intra-wave shfl_xor pre-reduce (4 k-slices/wave) -> red LDS is 1KB,
//     finisher reads are linear conflict-free.
//   - finisher = wave 0 only; vmcnt(0) drains ONLY the h stores; outs store
//     issued after the flag publish (no reader).
// Safety invariant (rounds 3/4, verified): every h address is written exactly
// once and read only after its producer's flag -> plain cached reads can never
// be stale; relaxed agent (sc1) atomics suffice. Waves 1-3 wait on their own
// WG's flag, which orders next-step hs/red overwrites after wave0's reads.

#define T_STEPS 2048
#define BATCH 16
#define DIM 1024
#define NDOM 4               // batch-quad domains
#define WPD 64               // WGs per domain
#define NWG (NDOM * WPD)     // 256 = one per CU
#define COLS 16              // output columns per WG
#define RSTRIDE 257          // float4 stride per 1024-float row (+16B pad)

__device__ __forceinline__ float dot4(float4 a, float4 b) {
    return a.x * b.x + a.y * b.y + a.z * b.z + a.w * b.w;
}

// ---------------- GEMM: C[m,n] = sum_k X[m,k]*W[n,k] + bias[n] ----------------
__global__ __launch_bounds__(256) void gemm_wx_kernel(
    const float* __restrict__ X,     // [M, K]
    const float* __restrict__ W,     // [N, K]
    const float* __restrict__ bias,  // [N]
    float* __restrict__ C)           // [M, N]
{
    const int K = DIM, N = DIM;
    __shared__ float Xs[64][17];
    __shared__ float Ws[64][17];
    const int tid = threadIdx.x;
    const int m0 = blockIdx.x * 64;
    const int n0 = blockIdx.y * 64;
    const int ty = tid >> 4;
    const int tx = tid & 15;
    float acc[4][4] = {};

    for (int k0 = 0; k0 < K; k0 += 16) {
#pragma unroll
        for (int i = 0; i < 4; i++) {
            int idx = tid + i * 256;
            int r = idx >> 4;
            int c = idx & 15;
            Xs[r][c] = X[(size_t)(m0 + r) * K + (k0 + c)];
            Ws[r][c] = W[(size_t)(n0 + r) * K + (k0 + c)];
        }
        __syncthreads();
#pragma unroll
        for (int kk = 0; kk < 16; kk++) {
            float a[4], w[4];
#pragma unroll
            for (int i = 0; i < 4; i++) a[i] = Xs[ty * 4 + i][kk];
#pragma unroll
            for (int j = 0; j < 4; j++) w[j] = Ws[tx * 4 + j][kk];
#pragma unroll
            for (int i = 0; i < 4; i++)
#pragma unroll
                for (int j = 0; j < 4; j++)
                    acc[i][j] += a[i] * w[j];
        }
        __syncthreads();
    }
#pragma unroll
    for (int i = 0; i < 4; i++) {
        int m = m0 + ty * 4 + i;
#pragma unroll
        for (int j = 0; j < 4; j++) {
            int n = n0 + tx * 4 + j;
            C[(size_t)m * N + n] = acc[i][j] + bias[n];
        }
    }
}

// ---------------- h[0] = h0 ----------------
__global__ __launch_bounds__(256) void copy_h0_kernel(
    const float* __restrict__ h0, float* __restrict__ h)
{
    int i = blockIdx.x * 256 + threadIdx.x;
    if (i < BATCH * DIM) h[i] = h0[i];
}

// ---------------- flag init (d_ws is poisoned each launch) ----------------
__global__ void flag_init_kernel(unsigned int* flags)
{
    flags[threadIdx.x] = 0u;   // 256 WG flags
}

// ---------------- persistent scan ----------------
// WG (dom = bid>>6, wgl = bid&63): cols [wgl*16, +16), batches [dom*4, +4).
// Thread map: pos = tid&15 (cp = pos&7 col-pair, bp = pos>>3 batch-pair),
//   ksf = tid>>4 (16 k-slices; k4 = ksf + 16*m, m=0..15). Wave w holds
//   ksf in [w*4, w*4+4) -> shfl_xor(16), shfl_xor(32) reduce within wave.
// Per thread: 4 accs = (col cp*2+cl, batch bp*2+bl), acc = cl*2+bl.
// red4[w*16+pos] holds the wave-reduced float4; finisher = wave 0, lane l:
//   pos = l>>2, acc = l&3  ->  rf[w*64 + l] linear reads, conflict-free.
__global__ __launch_bounds__(256, 1) void rnn_scan_kernel(
    const float* __restrict__ Wh,         // [D, D]
    const float* __restrict__ log_alpha,  // [1]
    float* __restrict__ outs,             // [T,B,D] (wx in, out overwritten)
    float* __restrict__ h,                // [T+1,B,D]
    unsigned int* __restrict__ flags)     // [NWG] WG flags (zeroed)
{
    __shared__ float4 whs4[COLS * RSTRIDE];   // 65.8 KB
    __shared__ float4 hs4[4 * RSTRIDE];       // 16.4 KB
    __shared__ float4 red4[64];               //  1.0 KB

    const int tid = threadIdx.x;
    const int bid = blockIdx.x;
    const int dom = bid >> 6;            // 0..3
    const int wgl = bid & 63;            // 0..63
    const int e0  = wgl * COLS;
    const int b0  = dom * 4;             // global batch base

    // ---- preload W_h rows for this WG (once) ----
    const float4* wh4 = (const float4*)Wh;
#pragma unroll
    for (int i = 0; i < 16; i++) {
        int idx = tid + i * 256;
        int r = idx >> 8, f = idx & 255;
        whs4[r * RSTRIDE + f] = wh4[(size_t)(e0 + r) * 256 + f];
    }
    const float alpha = expf(log_alpha[0]);
    __syncthreads();

    const int lane = tid & 63;
    const int w    = tid >> 6;
    const int pos  = tid & 15;
    const int cp   = pos & 7;
    const int bp   = pos >> 3;
    const int ksf  = tid >> 4;           // 0..15

    // LDS row bases (float4 units)
    const int wb0 = (cp * 2 + 0) * RSTRIDE;
    const int wb1 = (cp * 2 + 1) * RSTRIDE;
    const int hb0 = (bp * 2 + 0) * RSTRIDE;
    const int hb1 = (bp * 2 + 1) * RSTRIDE;

    // finisher mapping (wave 0, all 64 lanes -> the WG's 64 outputs)
    const int f_cl = (lane & 3) >> 1;
    const int f_bl = lane & 1;
    const int f_cp = (lane >> 2) & 7;
    const int f_bp = lane >> 5;
    const int f_e  = e0 + f_cp * 2 + f_cl;
    const int f_bL = f_bp * 2 + f_bl;    // local batch 0..3
    const int f_b  = b0 + f_bL;

    unsigned int* const fl = flags + dom * 64;
    unsigned int fv = __hip_atomic_load(&fl[lane], __ATOMIC_RELAXED,
                                        __HIP_MEMORY_SCOPE_AGENT);

    const float* hsF = (const float*)hs4;

    for (int t = 0; t < T_STEPS; t++) {
        // ---- wait: all 64 WGs of this domain have published h[t] ----
        while (__ballot(fv >= (unsigned)t) != ~0ull) {
            __builtin_amdgcn_s_sleep(1);
            fv = __hip_atomic_load(&fl[lane], __ATOMIC_RELAXED,
                                   __HIP_MEMORY_SCOPE_AGENT);
        }
        __builtin_amdgcn_sched_barrier(0);  // keep loads below the spin exit

        // ---- finisher prefetch wx (IC latency hides under stage+compute) ----
        float wx = 0.f;
        size_t oidx = 0;
        if (w == 0) {
            oidx = (size_t)t * (BATCH * DIM) + (size_t)f_b * DIM + f_e;
            wx = outs[oidx];
        }

        // ---- stage h[t] slice (4 batches, 16KB, coalesced float4) ----
        const float4* hp4 =
            (const float4*)(h + (size_t)t * (BATCH * DIM)) + (size_t)b0 * 256;
#pragma unroll
        for (int i = 0; i < 4; i++) {
            int idx = tid + i * 256;
            int b = idx >> 8, f = idx & 255;
            hs4[b * RSTRIDE + f] = hp4[idx];
        }
        __syncthreads();  // (A) hs ready

        // ---- partials: 2 cols x 2 batches per thread, 16 float4 k-steps ----
        float acc0 = 0.f, acc1 = 0.f, acc2 = 0.f, acc3 = 0.f;
#pragma unroll
        for (int m = 0; m < 16; m++) {
            const int k4 = ksf + 16 * m;
            float4 w0  = whs4[wb0 + k4];
            float4 w1  = whs4[wb1 + k4];
            float4 hv0 = hs4[hb0 + k4];
            float4 hv1 = hs4[hb1 + k4];
            acc0 += dot4(w0, hv0);
            acc1 += dot4(w0, hv1);
            acc2 += dot4(w1, hv0);
            acc3 += dot4(w1, hv1);
        }

        // ---- intra-wave reduce over ksf (lane bits 4,5) ----
        acc0 += __shfl_xor(acc0, 16); acc1 += __shfl_xor(acc1, 16);
        acc2 += __shfl_xor(acc2, 16); acc3 += __shfl_xor(acc3, 16);
        acc0 += __shfl_xor(acc0, 32); acc1 += __shfl_xor(acc1, 32);
        acc2 += __shfl_xor(acc2, 32); acc3 += __shfl_xor(acc3, 32);

        if (lane < 16) red4[w * 16 + pos] = make_float4(acc0, acc1, acc2, acc3);
        __syncthreads();  // (B) partials visible

        // ---- finish (wave 0): reduce 4 waves, nonlinearity, publish ----
        if (w == 0) {
            const float* rf = (const float*)red4;
            float s = rf[lane] + rf[64 + lane] + rf[128 + lane] + rf[192 + lane];
            const float hprev = hsF[f_bL * (RSTRIDE * 4) + f_e];
            const float pre  = s + wx;
            const float hnew = hprev + alpha * tanhf(pre);
            // agent-relaxed sc1 store -> Infinity Cache (agent coherence point)
            __hip_atomic_store(
                &h[(size_t)(t + 1) * (BATCH * DIM) + (size_t)f_b * DIM + f_e],
                hnew, __ATOMIC_RELAXED, __HIP_MEMORY_SCOPE_AGENT);
            // drain ONLY the h stores (wx/stage loads already consumed)
            asm volatile("s_waitcnt vmcnt(0)" ::: "memory");
            __hip_atomic_store(&fl[wgl], (unsigned)(t + 1),
                               __ATOMIC_RELAXED, __HIP_MEMORY_SCOPE_AGENT);
            // out store after the flag: nobody reads it; kernel-end drains it
            const float sig = 1.f / (1.f + expf(-hnew));
            outs[oidx] = hnew * hnew * sig;
        }

        // ---- prefetch next poll value (hides flag RTT) ----
        fv = __hip_atomic_load(&fl[lane], __ATOMIC_RELAXED,
                               __HIP_MEMORY_SCOPE_AGENT);
    }
}

extern "C" void kernel_launch(void* const* d_in, const int* in_sizes, int n_in,
                              void* d_out, int out_size, void* d_ws, size_t ws_size,
                              hipStream_t stream) {
    const float* x         = (const float*)d_in[0];  // [T,B,D]
    const float* h0        = (const float*)d_in[1];  // [B,D]
    const float* W_x       = (const float*)d_in[2];  // [D,D]
    const float* W_h       = (const float*)d_in[3];  // [D,D]
    const float* bias      = (const float*)d_in[4];  // [D]
    const float* log_alpha = (const float*)d_in[5];  // [1]

    float* outs = (float*)d_out;                                  // [T,B,D]
    float* h    = (float*)d_out + (size_t)T_STEPS * BATCH * DIM;  // [T+1,B,D]
    unsigned int* flags = (unsigned int*)d_ws;

    // 1) Wx_all (+bias) -> outs region. M = T*B = 32768 rows.
    dim3 ggrid(32768 / 64, DIM / 64);
    gemm_wx_kernel<<<ggrid, 256, 0, stream>>>(x, W_x, bias, outs);

    // 2) h[0] = h0 ; WG flags = 0
    copy_h0_kernel<<<(BATCH * DIM + 255) / 256, 256, 0, stream>>>(h0, h);
    flag_init_kernel<<<1, 256, 0, stream>>>(flags);

    // 3) persistent scan: 256 WGs = 1 per CU (83 KB LDS each)
    rnn_scan_kernel<<<NWG, 256, 0, stream>>>(W_h, log_alpha, outs, h, flags);
}